// Round 3
// baseline (2002.009 us; speedup 1.0000x reference)
//
#include <hip/hip_runtime.h>
#include <hip/hip_bf16.h>
#include <math.h>

// Transformer block. GEMMs via split-bf16 (bf16x3) MFMA emulation of fp32:
//   A ~= Ah + Al, B ~= Bh + Bl  (bf16 hi/lo planes)
//   C ~= Ah*Bh + Ah*Bl + Al*Bh   (error ~2^-17 relative)
// GEMM: 128x128 tile, BK=32, 4 waves, mfma_f32_16x16x32_bf16,
// global_load_lds(16B) staging, linear LDS (m97 structure).
// Attention: fp32 flash, 1 thread/q-row, float4 LDS broadcast + defer-max.
// RoPE: fp32-faithful cos/sin table (built once per call) + table-apply.

#define S_SEQ 2048
#define DM    1024
#define NH    16
#define DK    64
#define DFF   4096
#define T_TOK 4096

typedef short s16x8 __attribute__((ext_vector_type(8)));
typedef float f32x4 __attribute__((ext_vector_type(4)));

__device__ __forceinline__ unsigned short f32_to_bf16_rn(float f) {
  unsigned int u = __float_as_uint(f);
  unsigned int r = (u + 0x7FFFu + ((u >> 16) & 1u)) >> 16;
  return (unsigned short)r;
}
__device__ __forceinline__ float bf16_to_f32(unsigned short h) {
  return __uint_as_float(((unsigned int)h) << 16);
}

__device__ __forceinline__ void gload_lds16(const void* g, void* l) {
  __builtin_amdgcn_global_load_lds(
      (const __attribute__((address_space(1))) void*)g,
      (__attribute__((address_space(3))) void*)l, 16, 0, 0);
}

// ------------------------------------------------------------- rmsnorm -> planes
__global__ __launch_bounds__(256) void rmsnorm_planes(
    const float* __restrict__ x, const float* __restrict__ w,
    unsigned short* __restrict__ oh, unsigned short* __restrict__ ol)
{
  const int row = blockIdx.x;
  const int tid = threadIdx.x;
  const float4 v = ((const float4*)(x + (size_t)row * DM))[tid];
  float ss = v.x * v.x + v.y * v.y + v.z * v.z + v.w * v.w;
#pragma unroll
  for (int off = 32; off > 0; off >>= 1) ss += __shfl_xor(ss, off);
  __shared__ float red[4];
  if ((tid & 63) == 0) red[tid >> 6] = ss;
  __syncthreads();
  const float total = red[0] + red[1] + red[2] + red[3];
  const float scale = rsqrtf(total * (1.0f / DM) + 1e-5f);
  const float4 wv = ((const float4*)w)[tid];
  const float o0 = v.x * scale * wv.x, o1 = v.y * scale * wv.y;
  const float o2 = v.z * scale * wv.z, o3 = v.w * scale * wv.w;
  ushort4 h, l;
  h.x = f32_to_bf16_rn(o0); l.x = f32_to_bf16_rn(o0 - bf16_to_f32(h.x));
  h.y = f32_to_bf16_rn(o1); l.y = f32_to_bf16_rn(o1 - bf16_to_f32(h.y));
  h.z = f32_to_bf16_rn(o2); l.z = f32_to_bf16_rn(o2 - bf16_to_f32(h.z));
  h.w = f32_to_bf16_rn(o3); l.w = f32_to_bf16_rn(o3 - bf16_to_f32(h.w));
  ((ushort4*)(oh + (size_t)row * DM))[tid] = h;
  ((ushort4*)(ol + (size_t)row * DM))[tid] = l;
}

// ------------------------------------------------------------- fp32 -> planes
__global__ __launch_bounds__(256) void split_planes(
    const float* __restrict__ x, unsigned short* __restrict__ oh,
    unsigned short* __restrict__ ol, int n4)
{
  const int i = blockIdx.x * 256 + threadIdx.x;
  if (i >= n4) return;
  const float4 v = ((const float4*)x)[i];
  ushort4 h, l;
  h.x = f32_to_bf16_rn(v.x); l.x = f32_to_bf16_rn(v.x - bf16_to_f32(h.x));
  h.y = f32_to_bf16_rn(v.y); l.y = f32_to_bf16_rn(v.y - bf16_to_f32(h.y));
  h.z = f32_to_bf16_rn(v.z); l.z = f32_to_bf16_rn(v.z - bf16_to_f32(h.z));
  h.w = f32_to_bf16_rn(v.w); l.w = f32_to_bf16_rn(v.w - bf16_to_f32(h.w));
  ((ushort4*)oh)[i] = h;
  ((ushort4*)ol)[i] = l;
}

// ------------------------------------------------------------- split-bf16 MFMA GEMM
// C(MxN) = (Ah+Al)(MxK, row stride LDA) * (Bh+Bl)(NxK, row stride LDB)^T
// MODE 0: Cf = acc                MODE 1: Cf = auxF + acc
// MODE 2: planes = silu(acc)      MODE 3: planes = (auxH+auxL) .* acc
template <int MODE>
__global__ __launch_bounds__(256, 2) void gemm_sb(
    const unsigned short* __restrict__ Ah, const unsigned short* __restrict__ Al,
    const unsigned short* __restrict__ Bh, const unsigned short* __restrict__ Bl,
    const float* __restrict__ auxF,
    const unsigned short* __restrict__ auxH, const unsigned short* __restrict__ auxL,
    float* __restrict__ Cf, unsigned short* __restrict__ CH, unsigned short* __restrict__ CL,
    int N, int Kiter, int LDA, int LDB)
{
  __shared__ __align__(128) char lds[32768];
  constexpr int AHo = 0, ALo = 8192, BHo = 16384, BLo = 24576;

  const int nbn = N >> 7;
  int bid = blockIdx.x;
  const int cpx = gridDim.x >> 3;            // all grids are %8 == 0
  bid = (bid & 7) * cpx + (bid >> 3);        // XCD-contiguous swizzle (bijective)
  const int bmi = bid / nbn;
  const int bm = bmi << 7;
  const int bn = (bid - bmi * nbn) << 7;

  const int tid  = threadIdx.x;
  const int lane = tid & 63;
  const int wave = tid >> 6;
  const int wr = (wave >> 1) << 6;
  const int wc = (wave & 1) << 6;
  const int lrow = lane & 15;
  const int lk   = lane >> 4;

  // staging: 512 16B-chunks per plane tile (128 rows x 4 chunks), linear LDS.
  const int idx0 = tid, idx1 = tid + 256;
  const int r0 = idx0 >> 2, r1 = idx1 >> 2;
  const int c0 = idx0 & 3,  c1 = idx1 & 3;
  const size_t a0 = (size_t)(bm + r0) * LDA + c0 * 8;
  const size_t a1 = (size_t)(bm + r1) * LDA + c1 * 8;
  const size_t b0 = (size_t)(bn + r0) * LDB + c0 * 8;
  const size_t b1 = (size_t)(bn + r1) * LDB + c1 * 8;
  char* d0 = lds + idx0 * 16;
  char* d1 = lds + idx1 * 16;

  // fragment reads: row = (wr|wc) + f*16 + lrow, k-chunk = lk
  const int fro = lrow * 64 + (lk << 4);
  const char* pA = lds + AHo + wr * 64 + fro;
  const char* pB = lds + BHo + wc * 64 + fro;

  f32x4 acc[4][4] = {};

  for (int k0 = 0; k0 < Kiter; k0 += 32) {
    gload_lds16(Ah + a0 + k0, d0 + AHo);
    gload_lds16(Ah + a1 + k0, d1 + AHo);
    gload_lds16(Al + a0 + k0, d0 + ALo);
    gload_lds16(Al + a1 + k0, d1 + ALo);
    gload_lds16(Bh + b0 + k0, d0 + BHo);
    gload_lds16(Bh + b1 + k0, d1 + BHo);
    gload_lds16(Bl + b0 + k0, d0 + BLo);
    gload_lds16(Bl + b1 + k0, d1 + BLo);
    __syncthreads();

    s16x8 aH[4], aL[4], bH[4], bL[4];
#pragma unroll
    for (int f = 0; f < 4; ++f) {
      aH[f] = *(const s16x8*)(pA + f * 1024);
      aL[f] = *(const s16x8*)(pA + f * 1024 + (ALo - AHo));
      bH[f] = *(const s16x8*)(pB + f * 1024);
      bL[f] = *(const s16x8*)(pB + f * 1024 + (BLo - BHo));
    }
#pragma unroll
    for (int mi = 0; mi < 4; ++mi)
#pragma unroll
      for (int ni = 0; ni < 4; ++ni) {
        acc[mi][ni] = __builtin_amdgcn_mfma_f32_16x16x32_bf16(aH[mi], bH[ni], acc[mi][ni], 0, 0, 0);
        acc[mi][ni] = __builtin_amdgcn_mfma_f32_16x16x32_bf16(aH[mi], bL[ni], acc[mi][ni], 0, 0, 0);
        acc[mi][ni] = __builtin_amdgcn_mfma_f32_16x16x32_bf16(aL[mi], bH[ni], acc[mi][ni], 0, 0, 0);
      }
    __syncthreads();
  }

  // epilogue: C[row = (lane>>4)*4 + r][col = lane&15] per 16x16 fragment
#pragma unroll
  for (int mi = 0; mi < 4; ++mi) {
#pragma unroll
    for (int r = 0; r < 4; ++r) {
      const int row = bm + wr + mi * 16 + lk * 4 + r;
      const size_t rowo = (size_t)row * N;
#pragma unroll
      for (int ni = 0; ni < 4; ++ni) {
        const int col = bn + wc + ni * 16 + lrow;
        float v = acc[mi][ni][r];
        if constexpr (MODE == 1) v += auxF[rowo + col];
        if constexpr (MODE == 2) v = v / (1.0f + expf(-v));
        if constexpr (MODE == 3)
          v *= bf16_to_f32(auxH[rowo + col]) + bf16_to_f32(auxL[rowo + col]);
        if constexpr (MODE == 2 || MODE == 3) {
          const unsigned short hb = f32_to_bf16_rn(v);
          CH[rowo + col] = hb;
          CL[rowo + col] = f32_to_bf16_rn(v - bf16_to_f32(hb));
        } else {
          Cf[rowo + col] = v;
        }
      }
    }
  }
}

// ------------------------------------------------------------- RoPE table (once/call)
// tab[pos][i] = {cos, sin} of fp32(pos * fp32(10000^(-i/32)))   (fp32-faithful)
__global__ __launch_bounds__(256) void rope_table(float* __restrict__ tab)
{
  const int idx = blockIdx.x * 256 + threadIdx.x;   // 0 .. S*32-1
  const int pos = idx >> 5;
  const int i = idx & 31;
  const float ivf = (float)pow(10000.0, -(double)i / 32.0);
  const float angf = (float)((double)pos * (double)ivf);
  double sn, cs;
  sincos((double)angf, &sn, &cs);
  tab[idx * 2]     = (float)cs;
  tab[idx * 2 + 1] = (float)sn;
}

// ------------------------------------------------------------- RoPE apply (Q,K in-place)
__global__ __launch_bounds__(256) void rope_apply(
    float* __restrict__ Q, float* __restrict__ K, const float* __restrict__ tab)
{
  const int t = blockIdx.x;
  const int pos = t & (S_SEQ - 1);
  float* qr = Q + (size_t)t * DM;
  float* kr = K + (size_t)t * DM;
#pragma unroll
  for (int it = 0; it < 2; ++it) {
    const int p = threadIdx.x + it * 256;       // pair index 0..511
    const int i = p & 31;                       // freq index
    const int off = ((p >> 5) << 6) + (i << 1); // head*64 + 2i
    const float2 cst = ((const float2*)tab)[pos * 32 + i];
    const float c = cst.x, s = cst.y;
    const float qe = qr[off], qo = qr[off + 1];
    qr[off]     = qe * c - qo * s;
    qr[off + 1] = qe * s + qo * c;
    const float ke = kr[off], ko = kr[off + 1];
    kr[off]     = ke * c - ko * s;
    kr[off + 1] = ke * s + ko * c;
  }
}

// ------------------------------------------------------------- causal flash attention
// 1 thread per q row, 128 rows/block; 64x64 fp32 K/V tiles in LDS (stride 68);
// float4 broadcast reads; defer-max (skip rescale while s-m <= 8).
__global__ __launch_bounds__(128) void attn_kernel(
    const float* __restrict__ Q, const float* __restrict__ Kb,
    const float* __restrict__ Vb, unsigned short* __restrict__ OH,
    unsigned short* __restrict__ OL)
{
  const int h = blockIdx.y;
  const int b = blockIdx.z;
  const int q0 = blockIdx.x * 128;
  const int tid = threadIdx.x;
  const int qrow = q0 + tid;

  __shared__ float Ks[64 * 68];
  __shared__ float Vs[64 * 68];

  float q[64], o[64];
  const float* qp = Q + ((size_t)(b * S_SEQ + qrow)) * DM + h * DK;
#pragma unroll
  for (int d = 0; d < 64; d += 4) {
    const float4 v4 = *(const float4*)(qp + d);
    q[d] = v4.x * 0.125f; q[d + 1] = v4.y * 0.125f;
    q[d + 2] = v4.z * 0.125f; q[d + 3] = v4.w * 0.125f;
    o[d] = 0.f; o[d + 1] = 0.f; o[d + 2] = 0.f; o[d + 3] = 0.f;
  }
  float m = -1e30f, l = 0.f;

  for (int kt = 0; kt <= q0 + 127; kt += 64) {
#pragma unroll
    for (int i2 = 0; i2 < 8; ++i2) {
      const int slot = i2 * 128 + tid;          // 0..1023 float4 slots
      const int r = slot >> 4;
      const int c4 = (slot & 15) << 2;
      const size_t g = ((size_t)(b * S_SEQ + kt + r)) * DM + h * DK + c4;
      *(float4*)&Ks[r * 68 + c4] = *(const float4*)(Kb + g);
      *(float4*)&Vs[r * 68 + c4] = *(const float4*)(Vb + g);
    }
    __syncthreads();
    const int klim = min(64, qrow - kt + 1);    // <=0 -> no work this tile
    for (int kk = 0; kk < klim; ++kk) {
      const float* kr = &Ks[kk * 68];
      float s0 = 0.f, s1 = 0.f, s2 = 0.f, s3 = 0.f;
#pragma unroll
      for (int d = 0; d < 64; d += 4) {
        const float4 kx = *(const float4*)(kr + d);
        s0 = fmaf(q[d], kx.x, s0);
        s1 = fmaf(q[d + 1], kx.y, s1);
        s2 = fmaf(q[d + 2], kx.z, s2);
        s3 = fmaf(q[d + 3], kx.w, s3);
      }
      const float s = (s0 + s1) + (s2 + s3);
      if (__any((s - m) > 8.0f)) {              // T13 defer-max, wave-uniform
        const float mn = fmaxf(m, s);
        const float corr = __expf(m - mn);
        l *= corr;
#pragma unroll
        for (int d = 0; d < 64; ++d) o[d] *= corr;
        m = mn;
      }
      const float p = __expf(s - m);
      l += p;
      const float* vr = &Vs[kk * 68];
#pragma unroll
      for (int d = 0; d < 64; d += 4) {
        const float4 vx = *(const float4*)(vr + d);
        o[d]     = fmaf(p, vx.x, o[d]);
        o[d + 1] = fmaf(p, vx.y, o[d + 1]);
        o[d + 2] = fmaf(p, vx.z, o[d + 2]);
        o[d + 3] = fmaf(p, vx.w, o[d + 3]);
      }
    }
    __syncthreads();
  }
  const float inv = 1.0f / l;
  unsigned short* ohp = OH + ((size_t)(b * S_SEQ + qrow)) * DM + h * DK;
  unsigned short* olp = OL + ((size_t)(b * S_SEQ + qrow)) * DM + h * DK;
#pragma unroll
  for (int d = 0; d < 64; d += 4) {
    ushort4 hh, ll;
    const float v0 = o[d] * inv, v1 = o[d + 1] * inv;
    const float v2 = o[d + 2] * inv, v3 = o[d + 3] * inv;
    hh.x = f32_to_bf16_rn(v0); ll.x = f32_to_bf16_rn(v0 - bf16_to_f32(hh.x));
    hh.y = f32_to_bf16_rn(v1); ll.y = f32_to_bf16_rn(v1 - bf16_to_f32(hh.y));
    hh.z = f32_to_bf16_rn(v2); ll.z = f32_to_bf16_rn(v2 - bf16_to_f32(hh.z));
    hh.w = f32_to_bf16_rn(v3); ll.w = f32_to_bf16_rn(v3 - bf16_to_f32(hh.w));
    *(ushort4*)(ohp + d) = hh;
    *(ushort4*)(olp + d) = ll;
  }
}

// ------------------------------------------------------------- launch
extern "C" void kernel_launch(void* const* d_in, const int* in_sizes, int n_in,
                              void* d_out, int out_size, void* d_ws, size_t ws_size,
                              hipStream_t stream)
{
  const float* x   = (const float*)d_in[0];
  const float* Wq  = (const float*)d_in[1];
  const float* Wk  = (const float*)d_in[2];
  const float* Wv  = (const float*)d_in[3];
  const float* Wo  = (const float*)d_in[4];
  const float* ln1 = (const float*)d_in[5];
  const float* ln2 = (const float*)d_in[6];
  const float* w1  = (const float*)d_in[7];
  const float* w2  = (const float*)d_in[8];
  const float* w3  = (const float*)d_in[9];
  float* out = (float*)d_out;
  char* ws = (char*)d_ws;
  const size_t MB = 1024 * 1024;

  // ws layout, peak 160.5 MB:
  unsigned short* WqH = (unsigned short*)(ws + 0 * MB);
  unsigned short* WqL = (unsigned short*)(ws + 2 * MB);
  unsigned short* WkH = (unsigned short*)(ws + 4 * MB);
  unsigned short* WkL = (unsigned short*)(ws + 6 * MB);
  unsigned short* WvH = (unsigned short*)(ws + 8 * MB);
  unsigned short* WvL = (unsigned short*)(ws + 10 * MB);
  unsigned short* WoH = (unsigned short*)(ws + 12 * MB);
  unsigned short* WoL = (unsigned short*)(ws + 14 * MB);
  unsigned short* w1H = (unsigned short*)(ws + 16 * MB);
  unsigned short* w1L = (unsigned short*)(ws + 24 * MB);
  unsigned short* w2H = (unsigned short*)(ws + 32 * MB);
  unsigned short* w2L = (unsigned short*)(ws + 40 * MB);
  unsigned short* w3H = (unsigned short*)(ws + 48 * MB);
  unsigned short* w3L = (unsigned short*)(ws + 56 * MB);
  unsigned short* hH  = (unsigned short*)(ws + 64 * MB);
  unsigned short* hL  = (unsigned short*)(ws + 72 * MB);
  float* Qf = (float*)(ws + 80 * MB);
  float* Kf = (float*)(ws + 96 * MB);
  float* Vf = (float*)(ws + 112 * MB);
  unsigned short* ctxH = (unsigned short*)(ws + 128 * MB);
  unsigned short* ctxL = (unsigned short*)(ws + 136 * MB);
  float* x2  = (float*)(ws + 144 * MB);
  float* tab = (float*)(ws + 160 * MB);           // 512 KB RoPE table
  // FFN half-buffers (overlay Qf..ctx, dead by then):
  unsigned short* t1H = (unsigned short*)(ws + 80 * MB);
  unsigned short* t1L = (unsigned short*)(ws + 96 * MB);
  unsigned short* uH  = (unsigned short*)(ws + 112 * MB);
  unsigned short* uL  = (unsigned short*)(ws + 128 * MB);

  rope_table<<<256, 256, 0, stream>>>(tab);
  split_planes<<<1024, 256, 0, stream>>>(Wq, WqH, WqL, 1024 * 1024 / 4);
  split_planes<<<1024, 256, 0, stream>>>(Wk, WkH, WkL, 1024 * 1024 / 4);
  split_planes<<<1024, 256, 0, stream>>>(Wv, WvH, WvL, 1024 * 1024 / 4);
  split_planes<<<1024, 256, 0, stream>>>(Wo, WoH, WoL, 1024 * 1024 / 4);
  split_planes<<<4096, 256, 0, stream>>>(w1, w1H, w1L, 4096 * 1024 / 4);
  split_planes<<<4096, 256, 0, stream>>>(w2, w2H, w2L, 4096 * 1024 / 4);
  split_planes<<<4096, 256, 0, stream>>>(w3, w3H, w3L, 4096 * 1024 / 4);

  // 1) h = rmsnorm(x, ln1) -> planes
  rmsnorm_planes<<<T_TOK, 256, 0, stream>>>(x, ln1, hH, hL);
  // 2) Q,K,V (fp32)
  gemm_sb<0><<<256, 256, 0, stream>>>(hH, hL, WqH, WqL, nullptr, nullptr, nullptr, Qf, nullptr, nullptr, DM, DM, DM, DM);
  gemm_sb<0><<<256, 256, 0, stream>>>(hH, hL, WkH, WkL, nullptr, nullptr, nullptr, Kf, nullptr, nullptr, DM, DM, DM, DM);
  gemm_sb<0><<<256, 256, 0, stream>>>(hH, hL, WvH, WvL, nullptr, nullptr, nullptr, Vf, nullptr, nullptr, DM, DM, DM, DM);
  // 3) RoPE
  rope_apply<<<T_TOK, 256, 0, stream>>>(Qf, Kf, tab);
  // 4) ctx planes = attention(Q,K,V)
  attn_kernel<<<dim3(S_SEQ / 128, NH, 2), 128, 0, stream>>>(Qf, Kf, Vf, ctxH, ctxL);
  // 5) x2 = x + ctx @ Wo^T
  gemm_sb<1><<<256, 256, 0, stream>>>(ctxH, ctxL, WoH, WoL, x, nullptr, nullptr, x2, nullptr, nullptr, DM, DM, DM, DM);
  // 6) h2 = rmsnorm(x2, ln2) -> planes
  rmsnorm_planes<<<T_TOK, 256, 0, stream>>>(x2, ln2, hH, hL);
  // 7..9) FFN in two F-halves of 2048; d_out accumulates across halves
  for (int f = 0; f < 2; ++f) {
    const unsigned short* w1Hf = w1H + (size_t)f * 2048 * 1024;
    const unsigned short* w1Lf = w1L + (size_t)f * 2048 * 1024;
    const unsigned short* w3Hf = w3H + (size_t)f * 2048 * 1024;
    const unsigned short* w3Lf = w3L + (size_t)f * 2048 * 1024;
    // t1 = silu(h @ w1_f^T) -> planes (M=4096, N=2048)
    gemm_sb<2><<<512, 256, 0, stream>>>(hH, hL, w1Hf, w1Lf, nullptr, nullptr, nullptr, nullptr, t1H, t1L, 2048, DM, DM, DM);
    // u = t1 .* (h @ w3_f^T) -> planes
    gemm_sb<3><<<512, 256, 0, stream>>>(hH, hL, w3Hf, w3Lf, nullptr, t1H, t1L, nullptr, uH, uL, 2048, DM, DM, DM);
    // out = (f==0 ? x2 : out) + u @ w2[:, f-half]^T   (K=2048 slice of w2 rows)
    gemm_sb<1><<<256, 256, 0, stream>>>(uH, uL, w2H + (size_t)f * 2048, w2L + (size_t)f * 2048,
                                        (f == 0 ? x2 : out), nullptr, nullptr, out, nullptr, nullptr,
                                        DM, 2048, 2048, DFF);
  }
}

// Round 5
// 932.481 us; speedup vs baseline: 2.1470x; 2.1470x over previous
//
#include <hip/hip_runtime.h>
#include <hip/hip_bf16.h>
#include <math.h>

// Transformer block. All matmul-shaped compute via split-bf16 (bf16x3) MFMA
// emulation of fp32: A ~= Ah+Al, B ~= Bh+Bl, C ~= Ah*Bh + Ah*Bl + Al*Bh.
// GEMM: 128x128 tile, BK=32, 4 waves, mfma_f32_16x16x32_bf16 (m97 structure).
// Attention: MFMA flash, 4 waves x 16 q-rows, K-tile 64, XOR-swizzled LDS,
// P via LDS round-trip, V pre-transposed to [b][h][d][s] planes.
// ws peak exactly 160 MB (round-3 run proved ws_size >= 160.5 MB).

#define S_SEQ 2048
#define DM    1024
#define NH    16
#define DK    64
#define DFF   4096
#define T_TOK 4096

typedef short s16x8 __attribute__((ext_vector_type(8)));
typedef float f32x4 __attribute__((ext_vector_type(4)));

__device__ __forceinline__ unsigned short f32_to_bf16_rn(float f) {
  unsigned int u = __float_as_uint(f);
  unsigned int r = (u + 0x7FFFu + ((u >> 16) & 1u)) >> 16;
  return (unsigned short)r;
}
__device__ __forceinline__ float bf16_to_f32(unsigned short h) {
  return __uint_as_float(((unsigned int)h) << 16);
}

__device__ __forceinline__ void gload_lds16(const void* g, void* l) {
  __builtin_amdgcn_global_load_lds(
      (const __attribute__((address_space(1))) void*)g,
      (__attribute__((address_space(3))) void*)l, 16, 0, 0);
}

// ------------------------------------------------------------- rmsnorm -> planes
__global__ __launch_bounds__(256) void rmsnorm_planes(
    const float* __restrict__ x, const float* __restrict__ w,
    unsigned short* __restrict__ oh, unsigned short* __restrict__ ol)
{
  const int row = blockIdx.x;
  const int tid = threadIdx.x;
  const float4 v = ((const float4*)(x + (size_t)row * DM))[tid];
  float ss = v.x * v.x + v.y * v.y + v.z * v.z + v.w * v.w;
#pragma unroll
  for (int off = 32; off > 0; off >>= 1) ss += __shfl_xor(ss, off);
  __shared__ float red[4];
  if ((tid & 63) == 0) red[tid >> 6] = ss;
  __syncthreads();
  const float total = red[0] + red[1] + red[2] + red[3];
  const float scale = rsqrtf(total * (1.0f / DM) + 1e-5f);
  const float4 wv = ((const float4*)w)[tid];
  const float o0 = v.x * scale * wv.x, o1 = v.y * scale * wv.y;
  const float o2 = v.z * scale * wv.z, o3 = v.w * scale * wv.w;
  ushort4 h, l;
  h.x = f32_to_bf16_rn(o0); l.x = f32_to_bf16_rn(o0 - bf16_to_f32(h.x));
  h.y = f32_to_bf16_rn(o1); l.y = f32_to_bf16_rn(o1 - bf16_to_f32(h.y));
  h.z = f32_to_bf16_rn(o2); l.z = f32_to_bf16_rn(o2 - bf16_to_f32(h.z));
  h.w = f32_to_bf16_rn(o3); l.w = f32_to_bf16_rn(o3 - bf16_to_f32(h.w));
  ((ushort4*)(oh + (size_t)row * DM))[tid] = h;
  ((ushort4*)(ol + (size_t)row * DM))[tid] = l;
}

// ------------------------------------------------------------- fp32 -> planes
__global__ __launch_bounds__(256) void split_planes(
    const float* __restrict__ x, unsigned short* __restrict__ oh,
    unsigned short* __restrict__ ol, int n4)
{
  const int i = blockIdx.x * 256 + threadIdx.x;
  if (i >= n4) return;
  const float4 v = ((const float4*)x)[i];
  ushort4 h, l;
  h.x = f32_to_bf16_rn(v.x); l.x = f32_to_bf16_rn(v.x - bf16_to_f32(h.x));
  h.y = f32_to_bf16_rn(v.y); l.y = f32_to_bf16_rn(v.y - bf16_to_f32(h.y));
  h.z = f32_to_bf16_rn(v.z); l.z = f32_to_bf16_rn(v.z - bf16_to_f32(h.z));
  h.w = f32_to_bf16_rn(v.w); l.w = f32_to_bf16_rn(v.w - bf16_to_f32(h.w));
  ((ushort4*)oh)[i] = h;
  ((ushort4*)ol)[i] = l;
}

// ------------------------------------------------------------- split-bf16 MFMA GEMM
// C(MxN) = (Ah+Al)(MxK, stride LDA) * (Bh+Bl)(NxK, stride LDB)^T
// MODE 0: Cf = acc            MODE 1: Cf = auxF + acc
// MODE 2: planes = silu(acc)  MODE 3: planes = (auxH+auxL).*acc  MODE 4: planes = acc
template <int MODE>
__global__ __launch_bounds__(256, 2) void gemm_sb(
    const unsigned short* __restrict__ Ah, const unsigned short* __restrict__ Al,
    const unsigned short* __restrict__ Bh, const unsigned short* __restrict__ Bl,
    const float* __restrict__ auxF,
    const unsigned short* __restrict__ auxH, const unsigned short* __restrict__ auxL,
    float* __restrict__ Cf, unsigned short* __restrict__ CH, unsigned short* __restrict__ CL,
    int N, int Kiter, int LDA, int LDB)
{
  __shared__ __align__(128) char lds[32768];
  constexpr int AHo = 0, ALo = 8192, BHo = 16384, BLo = 24576;

  const int nbn = N >> 7;
  int bid = blockIdx.x;
  const int cpx = gridDim.x >> 3;            // all grids %8 == 0
  bid = (bid & 7) * cpx + (bid >> 3);        // XCD-contiguous swizzle
  const int bmi = bid / nbn;
  const int bm = bmi << 7;
  const int bn = (bid - bmi * nbn) << 7;

  const int tid  = threadIdx.x;
  const int lane = tid & 63;
  const int wave = tid >> 6;
  const int wr = (wave >> 1) << 6;
  const int wc = (wave & 1) << 6;
  const int lrow = lane & 15;
  const int lk   = lane >> 4;

  const int idx0 = tid, idx1 = tid + 256;
  const int r0 = idx0 >> 2, r1 = idx1 >> 2;
  const int c0 = idx0 & 3,  c1 = idx1 & 3;
  const size_t a0 = (size_t)(bm + r0) * LDA + c0 * 8;
  const size_t a1 = (size_t)(bm + r1) * LDA + c1 * 8;
  const size_t b0 = (size_t)(bn + r0) * LDB + c0 * 8;
  const size_t b1 = (size_t)(bn + r1) * LDB + c1 * 8;
  char* d0 = lds + idx0 * 16;
  char* d1 = lds + idx1 * 16;

  const int fro = lrow * 64 + (lk << 4);
  const char* pA = lds + AHo + wr * 64 + fro;
  const char* pB = lds + BHo + wc * 64 + fro;

  f32x4 acc[4][4] = {};

  for (int k0 = 0; k0 < Kiter; k0 += 32) {
    gload_lds16(Ah + a0 + k0, d0 + AHo);
    gload_lds16(Ah + a1 + k0, d1 + AHo);
    gload_lds16(Al + a0 + k0, d0 + ALo);
    gload_lds16(Al + a1 + k0, d1 + ALo);
    gload_lds16(Bh + b0 + k0, d0 + BHo);
    gload_lds16(Bh + b1 + k0, d1 + BHo);
    gload_lds16(Bl + b0 + k0, d0 + BLo);
    gload_lds16(Bl + b1 + k0, d1 + BLo);
    __syncthreads();

    s16x8 aH[4], aL[4], bH[4], bL[4];
#pragma unroll
    for (int f = 0; f < 4; ++f) {
      aH[f] = *(const s16x8*)(pA + f * 1024);
      aL[f] = *(const s16x8*)(pA + f * 1024 + (ALo - AHo));
      bH[f] = *(const s16x8*)(pB + f * 1024);
      bL[f] = *(const s16x8*)(pB + f * 1024 + (BLo - BHo));
    }
#pragma unroll
    for (int mi = 0; mi < 4; ++mi)
#pragma unroll
      for (int ni = 0; ni < 4; ++ni) {
        acc[mi][ni] = __builtin_amdgcn_mfma_f32_16x16x32_bf16(aH[mi], bH[ni], acc[mi][ni], 0, 0, 0);
        acc[mi][ni] = __builtin_amdgcn_mfma_f32_16x16x32_bf16(aH[mi], bL[ni], acc[mi][ni], 0, 0, 0);
        acc[mi][ni] = __builtin_amdgcn_mfma_f32_16x16x32_bf16(aL[mi], bH[ni], acc[mi][ni], 0, 0, 0);
      }
    __syncthreads();
  }

#pragma unroll
  for (int mi = 0; mi < 4; ++mi) {
#pragma unroll
    for (int r = 0; r < 4; ++r) {
      const int row = bm + wr + mi * 16 + lk * 4 + r;
      const size_t rowo = (size_t)row * N;
#pragma unroll
      for (int ni = 0; ni < 4; ++ni) {
        const int col = bn + wc + ni * 16 + lrow;
        float v = acc[mi][ni][r];
        if constexpr (MODE == 1) v += auxF[rowo + col];
        if constexpr (MODE == 2) v = v / (1.0f + expf(-v));
        if constexpr (MODE == 3)
          v *= bf16_to_f32(auxH[rowo + col]) + bf16_to_f32(auxL[rowo + col]);
        if constexpr (MODE >= 2) {
          const unsigned short hb = f32_to_bf16_rn(v);
          CH[rowo + col] = hb;
          CL[rowo + col] = f32_to_bf16_rn(v - bf16_to_f32(hb));
        } else {
          Cf[rowo + col] = v;
        }
      }
    }
  }
}

// ------------------------------------------------------------- RoPE table (once/call)
__global__ __launch_bounds__(256) void rope_table(float* __restrict__ tab)
{
  const int idx = blockIdx.x * 256 + threadIdx.x;   // 0 .. S*32-1
  const int pos = idx >> 5;
  const int i = idx & 31;
  const float ivf = (float)pow(10000.0, -(double)i / 32.0);
  const float angf = (float)((double)pos * (double)ivf);
  double sn, cs;
  sincos((double)angf, &sn, &cs);
  tab[idx * 2]     = (float)cs;
  tab[idx * 2 + 1] = (float)sn;
}

// ------------------------------------------------------------- RoPE on planes (in-place)
__global__ __launch_bounds__(256) void rope_apply_planes(
    unsigned short* __restrict__ QH, unsigned short* __restrict__ QL,
    unsigned short* __restrict__ KH, unsigned short* __restrict__ KL,
    const float* __restrict__ tab)
{
  const int t = blockIdx.x;
  const int pos = t & (S_SEQ - 1);
  const size_t rb = (size_t)t * DM;
#pragma unroll
  for (int it = 0; it < 2; ++it) {
    const int p = threadIdx.x + it * 256;       // pair 0..511
    const int i = p & 31;
    const int off = ((p >> 5) << 6) + (i << 1);
    const float2 cst = ((const float2*)tab)[pos * 32 + i];
    const float c = cst.x, s = cst.y;
#pragma unroll
    for (int qk = 0; qk < 2; ++qk) {
      unsigned short* H = qk ? KH : QH;
      unsigned short* L = qk ? KL : QL;
      const unsigned int vh = *(unsigned int*)(H + rb + off);
      const unsigned int vl = *(unsigned int*)(L + rb + off);
      const float e = bf16_to_f32((unsigned short)(vh & 0xffff)) +
                      bf16_to_f32((unsigned short)(vl & 0xffff));
      const float o = bf16_to_f32((unsigned short)(vh >> 16)) +
                      bf16_to_f32((unsigned short)(vl >> 16));
      const float ne = e * c - o * s;
      const float no = e * s + o * c;
      const unsigned short h0 = f32_to_bf16_rn(ne), h1 = f32_to_bf16_rn(no);
      const unsigned short l0 = f32_to_bf16_rn(ne - bf16_to_f32(h0));
      const unsigned short l1 = f32_to_bf16_rn(no - bf16_to_f32(h1));
      *(unsigned int*)(H + rb + off) = (unsigned)h0 | ((unsigned)h1 << 16);
      *(unsigned int*)(L + rb + off) = (unsigned)l0 | ((unsigned)l1 << 16);
    }
  }
}

// ------------------------------------------------------------- V -> V^T planes
// Vf [b][s][h*64+d] fp32  ->  Vt planes [(b*16+h)*64+d][s] bf16 hi/lo
__global__ __launch_bounds__(256) void vt_split(
    const float* __restrict__ Vf, unsigned short* __restrict__ VtH,
    unsigned short* __restrict__ VtL)
{
  __shared__ float T[64][65];
  const int b = blockIdx.z, h = blockIdx.y, s0 = blockIdx.x * 64;
  const int tid = threadIdx.x;
#pragma unroll
  for (int p = 0; p < 4; ++p) {
    const int idx = p * 256 + tid;       // 0..1023 float4 slots
    const int s = idx >> 4;
    const int d4 = (idx & 15) << 2;
    const float4 v = *(const float4*)(Vf + (size_t)(b * S_SEQ + s0 + s) * DM + h * 64 + d4);
    T[s][d4] = v.x; T[s][d4 + 1] = v.y; T[s][d4 + 2] = v.z; T[s][d4 + 3] = v.w;
  }
  __syncthreads();
  const int d = tid >> 2;
  const int sc = (tid & 3) << 4;
  unsigned int hw[8], lw[8];
#pragma unroll
  for (int j = 0; j < 8; ++j) {
    const float v0 = T[sc + 2 * j][d], v1 = T[sc + 2 * j + 1][d];
    const unsigned short h0 = f32_to_bf16_rn(v0), h1 = f32_to_bf16_rn(v1);
    const unsigned short l0 = f32_to_bf16_rn(v0 - bf16_to_f32(h0));
    const unsigned short l1 = f32_to_bf16_rn(v1 - bf16_to_f32(h1));
    hw[j] = (unsigned)h0 | ((unsigned)h1 << 16);
    lw[j] = (unsigned)l0 | ((unsigned)l1 << 16);
  }
  const size_t base = ((size_t)((b * NH + h) * 64 + d)) * S_SEQ + s0 + sc;
#pragma unroll
  for (int j = 0; j < 8; ++j) {
    *(unsigned int*)(VtH + base + 2 * j) = hw[j];
    *(unsigned int*)(VtL + base + 2 * j) = lw[j];
  }
}

// ------------------------------------------------------------- MFMA flash attention
// 4 waves x 16 q-rows, K-tile 64. K [key][dk] and Vt [d][key] tiles in LDS,
// XOR chunk-swizzled (chunk ^= row&7) via pre-swizzled global source.
__global__ __launch_bounds__(256, 3) void attn_mfma(
    const unsigned short* __restrict__ QH, const unsigned short* __restrict__ QL,
    const unsigned short* __restrict__ KH, const unsigned short* __restrict__ KL,
    const unsigned short* __restrict__ VtH, const unsigned short* __restrict__ VtL,
    unsigned short* __restrict__ ctxH, unsigned short* __restrict__ ctxL)
{
  __shared__ __align__(128) char lds[51200];
  // 0:KH[64][8c]  8192:KL  16384:VtH  24576:VtL  32768+w*4608: P planes (hi,lo)
  const int h = blockIdx.y, b = blockIdx.z;
  const int qt = 31 - blockIdx.x;            // LPT: big blocks first
  const int q0 = qt << 6;
  const int tid = threadIdx.x;
  const int lane = tid & 63;
  const int w = tid >> 6;
  const int lg = lane >> 4;                  // 0..3
  const int lr = lane & 15;

  // Q fragments: row = lr, k = kc*32 + lg*8 + j
  const size_t qtok = (size_t)(b * S_SEQ + q0 + w * 16 + lr);
  s16x8 qh[2], ql[2];
#pragma unroll
  for (int kc = 0; kc < 2; ++kc) {
    const size_t off = qtok * DM + h * 64 + kc * 32 + lg * 8;
    qh[kc] = *(const s16x8*)(QH + off);
    ql[kc] = *(const s16x8*)(QL + off);
  }

  f32x4 acc[4] = {};
  float mrow[4], lsum[4];
#pragma unroll
  for (int r = 0; r < 4; ++r) { mrow[r] = -1e30f; lsum[r] = 0.f; }

  unsigned short* PH = (unsigned short*)(lds + 32768 + w * 4608);
  unsigned short* PL = PH + 1152;
  const int wmax = q0 + w * 16 + 15;
  const int ntiles = qt + 1;

  for (int t = 0; t < ntiles; ++t) {
    const int kt = t << 6;
    // stage 4 planes x 512 chunks, source pre-swizzled (chunk ^= row&7)
#pragma unroll
    for (int pp = 0; pp < 8; ++pp) {
      const int idx = pp * 256 + tid;        // 0..2047
      const int plane = idx >> 9;            // 0..3
      const int ci = idx & 511;
      const int row = ci >> 3, pc = ci & 7;
      const int lc = pc ^ (row & 7);
      const unsigned short* src;
      if (plane == 0)      src = KH + (size_t)(b * S_SEQ + kt + row) * DM + h * 64 + lc * 8;
      else if (plane == 1) src = KL + (size_t)(b * S_SEQ + kt + row) * DM + h * 64 + lc * 8;
      else if (plane == 2) src = VtH + ((size_t)((b * NH + h) * 64 + row)) * S_SEQ + kt + lc * 8;
      else                 src = VtL + ((size_t)((b * NH + h) * 64 + row)) * S_SEQ + kt + lc * 8;
      gload_lds16(src, lds + plane * 8192 + ci * 16);
    }
    __syncthreads();

    if (kt <= wmax) {
      // ---- S = Q K^T (split-bf16) ----
      f32x4 s[4] = {};
      __builtin_amdgcn_s_setprio(1);
#pragma unroll
      for (int nf = 0; nf < 4; ++nf) {
        const int key = nf * 16 + lr;
#pragma unroll
        for (int kc = 0; kc < 2; ++kc) {
          const int pcx = (kc * 4 + lg) ^ (key & 7);
          const char* base = lds + key * 128 + pcx * 16;
          const s16x8 kh = *(const s16x8*)(base);
          const s16x8 kl = *(const s16x8*)(base + 8192);
          s[nf] = __builtin_amdgcn_mfma_f32_16x16x32_bf16(qh[kc], kh, s[nf], 0, 0, 0);
          s[nf] = __builtin_amdgcn_mfma_f32_16x16x32_bf16(qh[kc], kl, s[nf], 0, 0, 0);
          s[nf] = __builtin_amdgcn_mfma_f32_16x16x32_bf16(ql[kc], kh, s[nf], 0, 0, 0);
        }
      }
      __builtin_amdgcn_s_setprio(0);
      // ---- scale + causal mask ----
      const int myrow = q0 + w * 16 + 4 * lg;
#pragma unroll
      for (int nf = 0; nf < 4; ++nf) {
        const int key = kt + nf * 16 + lr;
#pragma unroll
        for (int r = 0; r < 4; ++r) {
          const float sv = s[nf][r] * 0.125f;
          s[nf][r] = (key <= myrow + r) ? sv : -__builtin_inff();
        }
      }
      // ---- online softmax (per row; 16-lane groups) ----
#pragma unroll
      for (int r = 0; r < 4; ++r) {
        float mx = fmaxf(fmaxf(s[0][r], s[1][r]), fmaxf(s[2][r], s[3][r]));
        mx = fmaxf(mx, __shfl_xor(mx, 1));
        mx = fmaxf(mx, __shfl_xor(mx, 2));
        mx = fmaxf(mx, __shfl_xor(mx, 4));
        mx = fmaxf(mx, __shfl_xor(mx, 8));
        const float mn = fmaxf(mrow[r], mx);
        const float corr = __expf(mrow[r] - mn);
        mrow[r] = mn;
        float ps = 0.f;
#pragma unroll
        for (int nf = 0; nf < 4; ++nf) {
          const float pv = __expf(s[nf][r] - mn);
          s[nf][r] = pv;
          ps += pv;
        }
        ps += __shfl_xor(ps, 1); ps += __shfl_xor(ps, 2);
        ps += __shfl_xor(ps, 4); ps += __shfl_xor(ps, 8);
        lsum[r] = lsum[r] * corr + ps;
#pragma unroll
        for (int nf = 0; nf < 4; ++nf) acc[nf][r] *= corr;
      }
      // ---- P -> bf16 planes -> LDS (C-layout write) ----
#pragma unroll
      for (int nf = 0; nf < 4; ++nf)
#pragma unroll
        for (int r = 0; r < 4; ++r) {
          const float pv = s[nf][r];
          const unsigned short ph = f32_to_bf16_rn(pv);
          const unsigned short pl = f32_to_bf16_rn(pv - bf16_to_f32(ph));
          const int pidx = (4 * lg + r) * 72 + nf * 16 + lr;
          PH[pidx] = ph; PL[pidx] = pl;
        }
      // ---- ctx += P V (A-layout read of P; Vt B-frags) ----
      __builtin_amdgcn_s_setprio(1);
#pragma unroll
      for (int kc = 0; kc < 2; ++kc) {
        const int eoff = lr * 72 + kc * 32 + lg * 8;
        const s16x8 pa = *(const s16x8*)(PH + eoff);
        const s16x8 pb = *(const s16x8*)(PL + eoff);
#pragma unroll
        for (int nf = 0; nf < 4; ++nf) {
          const int d = nf * 16 + lr;
          const int pcx = (kc * 4 + lg) ^ (d & 7);
          const char* vb = lds + 16384 + d * 128 + pcx * 16;
          const s16x8 vh = *(const s16x8*)(vb);
          const s16x8 vl = *(const s16x8*)(vb + 8192);
          acc[nf] = __builtin_amdgcn_mfma_f32_16x16x32_bf16(pa, vh, acc[nf], 0, 0, 0);
          acc[nf] = __builtin_amdgcn_mfma_f32_16x16x32_bf16(pa, vl, acc[nf], 0, 0, 0);
          acc[nf] = __builtin_amdgcn_mfma_f32_16x16x32_bf16(pb, vh, acc[nf], 0, 0, 0);
        }
      }
      __builtin_amdgcn_s_setprio(0);
    }
    __syncthreads();
  }
  // ---- epilogue: ctx planes ----
#pragma unroll
  for (int r = 0; r < 4; ++r) {
    const float inv = 1.0f / lsum[r];
    const size_t tok = (size_t)(b * S_SEQ + q0 + w * 16 + 4 * lg + r);
#pragma unroll
    for (int nf = 0; nf < 4; ++nf) {
      const float v = acc[nf][r] * inv;
      const unsigned short hb = f32_to_bf16_rn(v);
      const size_t o = tok * DM + h * 64 + nf * 16 + lr;
      ctxH[o] = hb;
      ctxL[o] = f32_to_bf16_rn(v - bf16_to_f32(hb));
    }
  }
}

// ------------------------------------------------------------- launch
extern "C" void kernel_launch(void* const* d_in, const int* in_sizes, int n_in,
                              void* d_out, int out_size, void* d_ws, size_t ws_size,
                              hipStream_t stream)
{
  const float* x   = (const float*)d_in[0];
  const float* Wq  = (const float*)d_in[1];
  const float* Wk  = (const float*)d_in[2];
  const float* Wv  = (const float*)d_in[3];
  const float* Wo  = (const float*)d_in[4];
  const float* ln1 = (const float*)d_in[5];
  const float* ln2 = (const float*)d_in[6];
  const float* w1  = (const float*)d_in[7];
  const float* w2  = (const float*)d_in[8];
  const float* w3  = (const float*)d_in[9];
  float* out = (float*)d_out;
  char* ws = (char*)d_ws;
  const size_t MB = 1024 * 1024;

  // ws layout, peak exactly 160 MB (phase-overlaid; round-3 proved >=160.5 MB ok)
  unsigned short* WqH = (unsigned short*)(ws + 0 * MB);
  unsigned short* WqL = (unsigned short*)(ws + 2 * MB);
  unsigned short* WkH = (unsigned short*)(ws + 4 * MB);
  unsigned short* WkL = (unsigned short*)(ws + 6 * MB);
  unsigned short* WvH = (unsigned short*)(ws + 8 * MB);
  unsigned short* WvL = (unsigned short*)(ws + 10 * MB);
  unsigned short* WoH = (unsigned short*)(ws + 12 * MB);
  unsigned short* WoL = (unsigned short*)(ws + 14 * MB);
  unsigned short* w1H = (unsigned short*)(ws + 16 * MB);
  unsigned short* w1L = (unsigned short*)(ws + 24 * MB);
  unsigned short* w2H = (unsigned short*)(ws + 32 * MB);
  unsigned short* w2L = (unsigned short*)(ws + 40 * MB);
  unsigned short* w3H = (unsigned short*)(ws + 48 * MB);
  unsigned short* w3L = (unsigned short*)(ws + 56 * MB);
  unsigned short* hH  = (unsigned short*)(ws + 64 * MB);
  unsigned short* hL  = (unsigned short*)(ws + 72 * MB);
  unsigned short* QHp = (unsigned short*)(ws + 80 * MB);   // live: QKV gemm -> attn
  unsigned short* QLp = (unsigned short*)(ws + 88 * MB);
  unsigned short* KHp = (unsigned short*)(ws + 96 * MB);
  unsigned short* KLp = (unsigned short*)(ws + 104 * MB);
  float* Vf = (float*)(ws + 112 * MB);                     // live: V gemm -> vt_split
  float* tab = (float*)(ws + 128 * MB);                    // live: start -> rope_apply
  unsigned short* VtH = (unsigned short*)(ws + 128 * MB);  // live: vt_split -> attn (overwrites tab)
  unsigned short* VtL = (unsigned short*)(ws + 136 * MB);
  unsigned short* ctxH = (unsigned short*)(ws + 144 * MB); // live: attn -> Wo gemm
  unsigned short* ctxL = (unsigned short*)(ws + 152 * MB);
  float* x2 = (float*)(ws + 80 * MB);                      // live: Wo gemm -> final (overlays Q planes)
  unsigned short* t1H = (unsigned short*)(ws + 96 * MB);   // FFN overlays (K/Vf/Vt/ctx dead)
  unsigned short* t1L = (unsigned short*)(ws + 112 * MB);
  unsigned short* uH  = (unsigned short*)(ws + 128 * MB);
  unsigned short* uL  = (unsigned short*)(ws + 144 * MB);

  rope_table<<<256, 256, 0, stream>>>(tab);
  split_planes<<<1024, 256, 0, stream>>>(Wq, WqH, WqL, 1024 * 1024 / 4);
  split_planes<<<1024, 256, 0, stream>>>(Wk, WkH, WkL, 1024 * 1024 / 4);
  split_planes<<<1024, 256, 0, stream>>>(Wv, WvH, WvL, 1024 * 1024 / 4);
  split_planes<<<1024, 256, 0, stream>>>(Wo, WoH, WoL, 1024 * 1024 / 4);
  split_planes<<<4096, 256, 0, stream>>>(w1, w1H, w1L, 4096 * 1024 / 4);
  split_planes<<<4096, 256, 0, stream>>>(w2, w2H, w2L, 4096 * 1024 / 4);
  split_planes<<<4096, 256, 0, stream>>>(w3, w3H, w3L, 4096 * 1024 / 4);

  // 1) h = rmsnorm(x, ln1) -> planes
  rmsnorm_planes<<<T_TOK, 256, 0, stream>>>(x, ln1, hH, hL);
  // 2) Q,K planes; V fp32
  gemm_sb<4><<<256, 256, 0, stream>>>(hH, hL, WqH, WqL, nullptr, nullptr, nullptr, nullptr, QHp, QLp, DM, DM, DM, DM);
  gemm_sb<4><<<256, 256, 0, stream>>>(hH, hL, WkH, WkL, nullptr, nullptr, nullptr, nullptr, KHp, KLp, DM, DM, DM, DM);
  gemm_sb<0><<<256, 256, 0, stream>>>(hH, hL, WvH, WvL, nullptr, nullptr, nullptr, Vf, nullptr, nullptr, DM, DM, DM, DM);
  // 3) RoPE on Q,K planes; then V^T planes (vt_split overwrites tab region)
  rope_apply_planes<<<T_TOK, 256, 0, stream>>>(QHp, QLp, KHp, KLp, tab);
  vt_split<<<dim3(32, NH, 2), 256, 0, stream>>>(Vf, VtH, VtL);
  // 4) ctx planes = causal attention
  attn_mfma<<<dim3(32, NH, 2), 256, 0, stream>>>(QHp, QLp, KHp, KLp, VtH, VtL, ctxH, ctxL);
  // 5) x2 = x + ctx @ Wo^T   (x2 overlays dead Q planes)
  gemm_sb<1><<<256, 256, 0, stream>>>(ctxH, ctxL, WoH, WoL, x, nullptr, nullptr, x2, nullptr, nullptr, DM, DM, DM, DM);
  // 6) h2 = rmsnorm(x2, ln2) -> planes
  rmsnorm_planes<<<T_TOK, 256, 0, stream>>>(x2, ln2, hH, hL);
  // 7..9) FFN in two F-halves; d_out accumulates
  for (int f = 0; f < 2; ++f) {
    const unsigned short* w1Hf = w1H + (size_t)f * 2048 * 1024;
    const unsigned short* w1Lf = w1L + (size_t)f * 2048 * 1024;
    const unsigned short* w3Hf = w3H + (size_t)f * 2048 * 1024;
    const unsigned short* w3Lf = w3L + (size_t)f * 2048 * 1024;
    gemm_sb<2><<<512, 256, 0, stream>>>(hH, hL, w1Hf, w1Lf, nullptr, nullptr, nullptr, nullptr, t1H, t1L, 2048, DM, DM, DM);
    gemm_sb<3><<<512, 256, 0, stream>>>(hH, hL, w3Hf, w3Lf, nullptr, t1H, t1L, nullptr, uH, uL, 2048, DM, DM, DM);
    gemm_sb<1><<<256, 256, 0, stream>>>(uH, uL, w2H + (size_t)f * 2048, w2L + (size_t)f * 2048,
                                        (f == 0 ? x2 : out), nullptr, nullptr, out, nullptr, nullptr,
                                        DM, 2048, 2048, DFF);
  }
}

// Round 8
// 749.380 us; speedup vs baseline: 2.6716x; 1.2443x over previous
//
#include <hip/hip_runtime.h>
#include <hip/hip_bf16.h>
#include <math.h>

// Transformer block. All matmul compute via split-bf16 (bf16x3) MFMA emulation
// of fp32: A ~= Ah+Al, B ~= Bh+Bl, C ~= Ah*Bh + Ah*Bl + Al*Bh.
// GEMM: 8-phase 256-row tile (m201-style): BK=32, 8 waves, dbuf LDS, counted
// vmcnt(2) (never 0 mid-loop), setprio around MFMA, chunk-XOR swizzle via
// pre-swizzled global source (both-sides involution, rule 21).
// Attention: MFMA flash, 4 waves x 16 q-rows, paired q-tiles (bx, 31-bx)
// for balanced 33-iteration blocks.
// Audited r6 (vmcnt ledger, dbuf WAR, bank math, residency, ws liveness) and
// r7 (async-DMA WAR window, barrier uniformity, asm reorder fences).
// Resubmission: rounds 5-7 all GPUAcquisitionTimeout; structure never executed.

#define S_SEQ 2048
#define DM    1024
#define NH    16
#define DFF   4096
#define T_TOK 4096

typedef short s16x8 __attribute__((ext_vector_type(8)));
typedef float f32x4 __attribute__((ext_vector_type(4)));

__device__ __forceinline__ unsigned short f32_to_bf16_rn(float f) {
  unsigned int u = __float_as_uint(f);
  unsigned int r = (u + 0x7FFFu + ((u >> 16) & 1u)) >> 16;
  return (unsigned short)r;
}
__device__ __forceinline__ float bf16_to_f32(unsigned short h) {
  return __uint_as_float(((unsigned int)h) << 16);
}

__device__ __forceinline__ void gload_lds16(const void* g, void* l) {
  __builtin_amdgcn_global_load_lds(
      (const __attribute__((address_space(1))) void*)g,
      (__attribute__((address_space(3))) void*)l, 16, 0, 0);
}

// ------------------------------------------------------------- rmsnorm -> planes
__global__ __launch_bounds__(256) void rmsnorm_planes(
    const float* __restrict__ x, const float* __restrict__ w,
    unsigned short* __restrict__ oh, unsigned short* __restrict__ ol)
{
  const int row = blockIdx.x;
  const int tid = threadIdx.x;
  const float4 v = ((const float4*)(x + (size_t)row * DM))[tid];
  float ss = v.x * v.x + v.y * v.y + v.z * v.z + v.w * v.w;
#pragma unroll
  for (int off = 32; off > 0; off >>= 1) ss += __shfl_xor(ss, off);
  __shared__ float red[4];
  if ((tid & 63) == 0) red[tid >> 6] = ss;
  __syncthreads();
  const float total = red[0] + red[1] + red[2] + red[3];
  const float scale = rsqrtf(total * (1.0f / DM) + 1e-5f);
  const float4 wv = ((const float4*)w)[tid];
  const float o0 = v.x * scale * wv.x, o1 = v.y * scale * wv.y;
  const float o2 = v.z * scale * wv.z, o3 = v.w * scale * wv.w;
  ushort4 h, l;
  h.x = f32_to_bf16_rn(o0); l.x = f32_to_bf16_rn(o0 - bf16_to_f32(h.x));
  h.y = f32_to_bf16_rn(o1); l.y = f32_to_bf16_rn(o1 - bf16_to_f32(h.y));
  h.z = f32_to_bf16_rn(o2); l.z = f32_to_bf16_rn(o2 - bf16_to_f32(h.z));
  h.w = f32_to_bf16_rn(o3); l.w = f32_to_bf16_rn(o3 - bf16_to_f32(h.w));
  ((ushort4*)(oh + (size_t)row * DM))[tid] = h;
  ((ushort4*)(ol + (size_t)row * DM))[tid] = l;
}

// ------------------------------------------------------------- fp32 -> planes
__global__ __launch_bounds__(256) void split_planes(
    const float* __restrict__ x, unsigned short* __restrict__ oh,
    unsigned short* __restrict__ ol, int n4)
{
  const int i = blockIdx.x * 256 + threadIdx.x;
  if (i >= n4) return;
  const float4 v = ((const float4*)x)[i];
  ushort4 h, l;
  h.x = f32_to_bf16_rn(v.x); l.x = f32_to_bf16_rn(v.x - bf16_to_f32(h.x));
  h.y = f32_to_bf16_rn(v.y); l.y = f32_to_bf16_rn(v.y - bf16_to_f32(h.y));
  h.z = f32_to_bf16_rn(v.z); l.z = f32_to_bf16_rn(v.z - bf16_to_f32(h.z));
  h.w = f32_to_bf16_rn(v.w); l.w = f32_to_bf16_rn(v.w - bf16_to_f32(h.w));
  ((ushort4*)oh)[i] = h;
  ((ushort4*)ol)[i] = l;
}

// ------------------------------------------------------------- 8-phase split-bf16 GEMM
// C(MxN) = (Ah+Al)(MxK,row LDA) * (Bh+Bl)(NxK,row LDB)^T, BM=256, BK=32, 8 waves.
// MODE 1: Cf = auxF + acc
// MODE 2: planes(CH,CL) = split(silu(acc))
// MODE 3: planes(CH,CL) = split(acc * (CH+CL))   [in-place multiply]
// MODE 5: QKV route: cols [0,1024)->CH/CL, [1024,2048)->C2, [2048,3072)->C3
template <int BN, int MODE>
__global__ __launch_bounds__(512, 2) void gemm8(
    const unsigned short* __restrict__ Ah, const unsigned short* __restrict__ Al,
    const unsigned short* __restrict__ Bh, const unsigned short* __restrict__ Bl,
    const float* __restrict__ auxF, float* __restrict__ Cf,
    unsigned short* __restrict__ CH, unsigned short* __restrict__ CL,
    unsigned short* __restrict__ C2H, unsigned short* __restrict__ C2L,
    unsigned short* __restrict__ C3H, unsigned short* __restrict__ C3L,
    int N, int K, int LDA, int LDB, int nbn)
{
  constexpr int NF = BN / 64;              // n-fragments per wave
  constexpr int WNS = BN / 4;              // wave n-span
  constexpr int ABYT = 256 * 32 * 2;       // 16384 B per A plane tile
  constexpr int BBYT = BN * 32 * 2;        // B plane tile bytes
  constexpr int AHo = 0, ALo = ABYT, BHo = 2 * ABYT, BLo = 2 * ABYT + BBYT;
  constexpr int BUFSZ = 2 * ABYT + 2 * BBYT;
  __shared__ __align__(128) char lds[2 * BUFSZ];

  const int tid = threadIdx.x;
  const int lane = tid & 63;
  const int wave = tid >> 6;
  const int wm = wave >> 2, wn = wave & 3;
  const int lr = lane & 15, lg = lane >> 4;
  const int koff = ((lg ^ ((lr >> 1) & 3)) << 4);   // chunk swizzle on read

  int bid = blockIdx.x;
  const int cpx = gridDim.x >> 3;           // all grids %8 == 0
  bid = (bid & 7) * cpx + (bid >> 3);       // XCD-contiguous swizzle (bijective)
  const int bmi = bid / nbn;
  const int bm = bmi << 8;
  const int bn = (bid - bmi * nbn) * BN;

  // staging: chunk c -> lds slot c*16; global source chunk col = (c&3)^((row>>1)&3)
  const int cA0 = tid, cA1 = tid + 512;
  const int rA0 = cA0 >> 2, rA1 = cA1 >> 2;
  const int sA0 = (bm + rA0) * LDA + (((cA0 & 3) ^ ((rA0 >> 1) & 3)) << 3);
  const int sA1 = (bm + rA1) * LDA + (((cA1 & 3) ^ ((rA1 >> 1) & 3)) << 3);
  const int dA0 = cA0 * 16, dA1 = cA1 * 16;
  const int rB0 = cA0 >> 2;
  const int sB0 = (bn + rB0) * LDB + (((cA0 & 3) ^ ((rB0 >> 1) & 3)) << 3);
  const int dB0 = cA0 * 16;
  const int rB1 = cA1 >> 2;                  // only dereferenced when BN==256
  const int sB1 = (bn + rB1) * LDB + (((cA1 & 3) ^ ((rB1 >> 1) & 3)) << 3);
  const int dB1 = cA1 * 16;

  f32x4 acc[8][NF] = {};

  // prologue: stage tile 0 into buffer 0 (8 loads BN=256 / 6 loads BN=128)
  gload_lds16(Ah + sA0, lds + AHo + dA0);
  gload_lds16(Ah + sA1, lds + AHo + dA1);
  gload_lds16(Al + sA0, lds + ALo + dA0);
  gload_lds16(Al + sA1, lds + ALo + dA1);
  gload_lds16(Bh + sB0, lds + BHo + dB0);
  if constexpr (BN == 256) gload_lds16(Bh + sB1, lds + BHo + dB1);
  gload_lds16(Bl + sB0, lds + BLo + dB0);
  if constexpr (BN == 256) gload_lds16(Bl + sB1, lds + BLo + dB1);

  const int NT = K >> 5;
  const int arow = (wm * 128 + lr) * 64 + koff;
  const int brow = (wn * WNS + lr) * 64 + koff;

  for (int t = 0; t < NT; ++t) {
    char* L  = lds + (t & 1) * BUFSZ;
    char* Ln = lds + ((t + 1) & 1) * BUFSZ;
    const int kn = (t + 1) << 5;
    const bool pf = (t + 1 < NT);
    s16x8 bh[NF], bl[NF];

#pragma unroll
    for (int p = 0; p < 4; ++p) {
      // -------- prefetch issue for tile t+1 (2/phase; BN=128: 2,2,1,1)
      if (p == 0 && pf) {
        gload_lds16(Ah + sA0 + kn, Ln + AHo + dA0);
        gload_lds16(Ah + sA1 + kn, Ln + AHo + dA1);
      }
      if (p == 1 && pf) {
        gload_lds16(Al + sA0 + kn, Ln + ALo + dA0);
        gload_lds16(Al + sA1 + kn, Ln + ALo + dA1);
      }
      if (p == 2 && pf) {
        gload_lds16(Bh + sB0 + kn, Ln + BHo + dB0);
        if constexpr (BN == 256) gload_lds16(Bh + sB1 + kn, Ln + BHo + dB1);
      }
      if (p == 3 && pf) {
        gload_lds16(Bl + sB0 + kn, Ln + BLo + dB0);
        if constexpr (BN == 256) gload_lds16(Bl + sB1 + kn, Ln + BLo + dB1);
      }
      if (p == 0) {
        // counted wait: previous tile fully staged; just-issued 2 stay in flight
        if (pf) asm volatile("s_waitcnt vmcnt(2)" ::: "memory");
        else    asm volatile("s_waitcnt vmcnt(0)" ::: "memory");
        __builtin_amdgcn_sched_barrier(0);
        __builtin_amdgcn_s_barrier();
      }
      // -------- ds reads for this phase
      if (p == 0) {
#pragma unroll
        for (int nf = 0; nf < NF; ++nf) {
          bh[nf] = *(const s16x8*)(L + BHo + brow + nf * 1024);
          bl[nf] = *(const s16x8*)(L + BLo + brow + nf * 1024);
        }
      }
      const s16x8 a0h = *(const s16x8*)(L + AHo + arow + p * 2048);
      const s16x8 a0l = *(const s16x8*)(L + ALo + arow + p * 2048);
      const s16x8 a1h = *(const s16x8*)(L + AHo + arow + p * 2048 + 1024);
      const s16x8 a1l = *(const s16x8*)(L + ALo + arow + p * 2048 + 1024);
      asm volatile("s_waitcnt lgkmcnt(0)" ::: "memory");
      __builtin_amdgcn_sched_barrier(0);
      __builtin_amdgcn_s_setprio(1);
#pragma unroll
      for (int nf = 0; nf < NF; ++nf) {
        acc[2 * p][nf] = __builtin_amdgcn_mfma_f32_16x16x32_bf16(a0h, bh[nf], acc[2 * p][nf], 0, 0, 0);
        acc[2 * p][nf] = __builtin_amdgcn_mfma_f32_16x16x32_bf16(a0h, bl[nf], acc[2 * p][nf], 0, 0, 0);
        acc[2 * p][nf] = __builtin_amdgcn_mfma_f32_16x16x32_bf16(a0l, bh[nf], acc[2 * p][nf], 0, 0, 0);
        acc[2 * p + 1][nf] = __builtin_amdgcn_mfma_f32_16x16x32_bf16(a1h, bh[nf], acc[2 * p + 1][nf], 0, 0, 0);
        acc[2 * p + 1][nf] = __builtin_amdgcn_mfma_f32_16x16x32_bf16(a1h, bl[nf], acc[2 * p + 1][nf], 0, 0, 0);
        acc[2 * p + 1][nf] = __builtin_amdgcn_mfma_f32_16x16x32_bf16(a1l, bh[nf], acc[2 * p + 1][nf], 0, 0, 0);
      }
      __builtin_amdgcn_s_setprio(0);
      __builtin_amdgcn_s_barrier();
    }
  }

  // -------- epilogue: C[row=(lane>>4)*4+r][col=lane&15] per fragment
  unsigned short* oH = CH;
  unsigned short* oL = CL;
  int coff = 0;
  if constexpr (MODE == 5) {
    const int seg = bn >> 10;
    coff = seg << 10;
    if (seg == 1) { oH = C2H; oL = C2L; }
    else if (seg == 2) { oH = C3H; oL = C3L; }
  }
#pragma unroll
  for (int mf = 0; mf < 8; ++mf) {
#pragma unroll
    for (int r = 0; r < 4; ++r) {
      const int row = bm + wm * 128 + mf * 16 + lg * 4 + r;
#pragma unroll
      for (int nf = 0; nf < NF; ++nf) {
        const int col = bn + wn * WNS + nf * 16 + lr;
        float v = acc[mf][nf][r];
        if constexpr (MODE == 1) {
          const size_t idx = (size_t)row * N + col;
          Cf[idx] = auxF[idx] + v;
        } else if constexpr (MODE == 2) {
          const size_t idx = (size_t)row * N + col;
          v = v / (1.0f + expf(-v));
          const unsigned short hb = f32_to_bf16_rn(v);
          CH[idx] = hb;
          CL[idx] = f32_to_bf16_rn(v - bf16_to_f32(hb));
        } else if constexpr (MODE == 3) {
          const size_t idx = (size_t)row * N + col;
          v *= bf16_to_f32(CH[idx]) + bf16_to_f32(CL[idx]);
          const unsigned short hb = f32_to_bf16_rn(v);
          CH[idx] = hb;
          CL[idx] = f32_to_bf16_rn(v - bf16_to_f32(hb));
        } else {  // MODE 5
          const size_t idx = (size_t)row * 1024 + (col - coff);
          const unsigned short hb = f32_to_bf16_rn(v);
          oH[idx] = hb;
          oL[idx] = f32_to_bf16_rn(v - bf16_to_f32(hb));
        }
      }
    }
  }
}

// ------------------------------------------------------------- RoPE table (once/call)
__global__ __launch_bounds__(256) void rope_table(float* __restrict__ tab)
{
  const int idx = blockIdx.x * 256 + threadIdx.x;   // 0 .. S*32-1
  const int pos = idx >> 5;
  const int i = idx & 31;
  const float ivf = (float)pow(10000.0, -(double)i / 32.0);
  const float angf = (float)((double)pos * (double)ivf);
  double sn, cs;
  sincos((double)angf, &sn, &cs);
  tab[idx * 2]     = (float)cs;
  tab[idx * 2 + 1] = (float)sn;
}

// ------------------------------------------------------------- RoPE on planes (in-place)
__global__ __launch_bounds__(256) void rope_apply_planes(
    unsigned short* __restrict__ QH, unsigned short* __restrict__ QL,
    unsigned short* __restrict__ KH, unsigned short* __restrict__ KL,
    const float* __restrict__ tab)
{
  const int t = blockIdx.x;
  const int pos = t & (S_SEQ - 1);
  const size_t rb = (size_t)t * DM;
#pragma unroll
  for (int it = 0; it < 2; ++it) {
    const int p = threadIdx.x + it * 256;
    const int i = p & 31;
    const int off = ((p >> 5) << 6) + (i << 1);
    const float2 cst = ((const float2*)tab)[pos * 32 + i];
    const float c = cst.x, s = cst.y;
#pragma unroll
    for (int qk = 0; qk < 2; ++qk) {
      unsigned short* H = qk ? KH : QH;
      unsigned short* L = qk ? KL : QL;
      const unsigned int vh = *(unsigned int*)(H + rb + off);
      const unsigned int vl = *(unsigned int*)(L + rb + off);
      const float e = bf16_to_f32((unsigned short)(vh & 0xffff)) +
                      bf16_to_f32((unsigned short)(vl & 0xffff));
      const float o = bf16_to_f32((unsigned short)(vh >> 16)) +
                      bf16_to_f32((unsigned short)(vl >> 16));
      const float ne = e * c - o * s;
      const float no = e * s + o * c;
      const unsigned short h0 = f32_to_bf16_rn(ne), h1 = f32_to_bf16_rn(no);
      const unsigned short l0 = f32_to_bf16_rn(ne - bf16_to_f32(h0));
      const unsigned short l1 = f32_to_bf16_rn(no - bf16_to_f32(h1));
      *(unsigned int*)(H + rb + off) = (unsigned)h0 | ((unsigned)h1 << 16);
      *(unsigned int*)(L + rb + off) = (unsigned)l0 | ((unsigned)l1 << 16);
    }
  }
}

// ------------------------------------------------------------- V planes -> V^T planes
__global__ __launch_bounds__(256) void vt_split(
    const unsigned short* __restrict__ VH, const unsigned short* __restrict__ VL,
    unsigned short* __restrict__ VtH, unsigned short* __restrict__ VtL)
{
  __shared__ float T[64][65];
  const int b = blockIdx.z, h = blockIdx.y, s0 = blockIdx.x * 64;
  const int tid = threadIdx.x;
#pragma unroll
  for (int p = 0; p < 4; ++p) {
    const int idx = p * 256 + tid;
    const int s = idx >> 4;
    const int d4 = (idx & 15) << 2;
    const size_t g = (size_t)(b * S_SEQ + s0 + s) * DM + h * 64 + d4;
    const ushort4 a = *(const ushort4*)(VH + g);
    const ushort4 c = *(const ushort4*)(VL + g);
    T[s][d4]     = bf16_to_f32(a.x) + bf16_to_f32(c.x);
    T[s][d4 + 1] = bf16_to_f32(a.y) + bf16_to_f32(c.y);
    T[s][d4 + 2] = bf16_to_f32(a.z) + bf16_to_f32(c.z);
    T[s][d4 + 3] = bf16_to_f32(a.w) + bf16_to_f32(c.w);
  }
  __syncthreads();
  const int d = tid >> 2;
  const int sc = (tid & 3) << 4;
  unsigned int hw[8], lw[8];
#pragma unroll
  for (int j = 0; j < 8; ++j) {
    const float v0 = T[sc + 2 * j][d], v1 = T[sc + 2 * j + 1][d];
    const unsigned short h0 = f32_to_bf16_rn(v0), h1 = f32_to_bf16_rn(v1);
    const unsigned short l0 = f32_to_bf16_rn(v0 - bf16_to_f32(h0));
    const unsigned short l1 = f32_to_bf16_rn(v1 - bf16_to_f32(h1));
    hw[j] = (unsigned)h0 | ((unsigned)h1 << 16);
    lw[j] = (unsigned)l0 | ((unsigned)l1 << 16);
  }
  const size_t base = ((size_t)((b * NH + h) * 64 + d)) * S_SEQ + s0 + sc;
#pragma unroll
  for (int j = 0; j < 8; ++j) {
    *(unsigned int*)(VtH + base + 2 * j) = hw[j];
    *(unsigned int*)(VtL + base + 2 * j) = lw[j];
  }
}

// ------------------------------------------------------------- MFMA flash attention
// 4 waves x 16 q-rows; paired q-tiles (bx, 31-bx) per block -> balanced 33 iters.
__global__ __launch_bounds__(256, 3) void attn_mfma(
    const unsigned short* __restrict__ QH, const unsigned short* __restrict__ QL,
    const unsigned short* __restrict__ KH, const unsigned short* __restrict__ KL,
    const unsigned short* __restrict__ VtH, const unsigned short* __restrict__ VtL,
    unsigned short* __restrict__ ctxH, unsigned short* __restrict__ ctxL)
{
  __shared__ __align__(128) char lds[51200];
  const int h = blockIdx.y, b = blockIdx.z;
  const int tid = threadIdx.x;
  const int lane = tid & 63;
  const int w = tid >> 6;
  const int lg = lane >> 4;
  const int lr = lane & 15;

  unsigned short* PH = (unsigned short*)(lds + 32768 + w * 4608);
  unsigned short* PL = PH + 1152;

  for (int pi = 0; pi < 2; ++pi) {
    const int qt = pi ? (31 - blockIdx.x) : blockIdx.x;
    const int q0 = qt << 6;

    const size_t qtok = (size_t)(b * S_SEQ + q0 + w * 16 + lr);
    s16x8 qh[2], ql[2];
#pragma unroll
    for (int kc = 0; kc < 2; ++kc) {
      const size_t off = qtok * DM + h * 64 + kc * 32 + lg * 8;
      qh[kc] = *(const s16x8*)(QH + off);
      ql[kc] = *(const s16x8*)(QL + off);
    }

    f32x4 acc[4] = {};
    float mrow[4], lsum[4];
#pragma unroll
    for (int r = 0; r < 4; ++r) { mrow[r] = -1e30f; lsum[r] = 0.f; }

    const int wmax = q0 + w * 16 + 15;
    const int ntiles = qt + 1;

    for (int t = 0; t < ntiles; ++t) {
      const int kt = t << 6;
#pragma unroll
      for (int pp = 0; pp < 8; ++pp) {
        const int idx = pp * 256 + tid;
        const int plane = idx >> 9;
        const int ci = idx & 511;
        const int row = ci >> 3, pc = ci & 7;
        const int lc = pc ^ (row & 7);
        const unsigned short* src;
        if (plane == 0)      src = KH + (size_t)(b * S_SEQ + kt + row) * DM + h * 64 + lc * 8;
        else if (plane == 1) src = KL + (size_t)(b * S_SEQ + kt + row) * DM + h * 64 + lc * 8;
        else if (plane == 2) src = VtH + ((size_t)((b * NH + h) * 64 + row)) * S_SEQ + kt + lc * 8;
        else                 src = VtL + ((size_t)((b * NH + h) * 64 + row)) * S_SEQ + kt + lc * 8;
        gload_lds16(src, lds + plane * 8192 + ci * 16);
      }
      __syncthreads();

      if (kt <= wmax) {
        f32x4 s[4] = {};
        __builtin_amdgcn_s_setprio(1);
#pragma unroll
        for (int nf = 0; nf < 4; ++nf) {
          const int key = nf * 16 + lr;
#pragma unroll
          for (int kc = 0; kc < 2; ++kc) {
            const int pcx = (kc * 4 + lg) ^ (key & 7);
            const char* base = lds + key * 128 + pcx * 16;
            const s16x8 kh = *(const s16x8*)(base);
            const s16x8 kl = *(const s16x8*)(base + 8192);
            s[nf] = __builtin_amdgcn_mfma_f32_16x16x32_bf16(qh[kc], kh, s[nf], 0, 0, 0);
            s[nf] = __builtin_amdgcn_mfma_f32_16x16x32_bf16(qh[kc], kl, s[nf], 0, 0, 0);
            s[nf] = __builtin_amdgcn_mfma_f32_16x16x32_bf16(ql[kc], kh, s[nf], 0, 0, 0);
          }
        }
        __builtin_amdgcn_s_setprio(0);
        const int myrow = q0 + w * 16 + 4 * lg;
#pragma unroll
        for (int nf = 0; nf < 4; ++nf) {
          const int key = kt + nf * 16 + lr;
#pragma unroll
          for (int r = 0; r < 4; ++r) {
            const float sv = s[nf][r] * 0.125f;
            s[nf][r] = (key <= myrow + r) ? sv : -__builtin_inff();
          }
        }
#pragma unroll
        for (int r = 0; r < 4; ++r) {
          float mx = fmaxf(fmaxf(s[0][r], s[1][r]), fmaxf(s[2][r], s[3][r]));
          mx = fmaxf(mx, __shfl_xor(mx, 1));
          mx = fmaxf(mx, __shfl_xor(mx, 2));
          mx = fmaxf(mx, __shfl_xor(mx, 4));
          mx = fmaxf(mx, __shfl_xor(mx, 8));
          const float mn = fmaxf(mrow[r], mx);
          const float corr = __expf(mrow[r] - mn);
          mrow[r] = mn;
          float ps = 0.f;
#pragma unroll
          for (int nf = 0; nf < 4; ++nf) {
            const float pv = __expf(s[nf][r] - mn);
            s[nf][r] = pv;
            ps += pv;
          }
          ps += __shfl_xor(ps, 1); ps += __shfl_xor(ps, 2);
          ps += __shfl_xor(ps, 4); ps += __shfl_xor(ps, 8);
          lsum[r] = lsum[r] * corr + ps;
#pragma unroll
          for (int nf = 0; nf < 4; ++nf) acc[nf][r] *= corr;
        }
#pragma unroll
        for (int nf = 0; nf < 4; ++nf)
#pragma unroll
          for (int r = 0; r < 4; ++r) {
            const float pv = s[nf][r];
            const unsigned short ph = f32_to_bf16_rn(pv);
            const unsigned short pl = f32_to_bf16_rn(pv - bf16_to_f32(ph));
            const int pidx = (4 * lg + r) * 72 + nf * 16 + lr;
            PH[pidx] = ph; PL[pidx] = pl;
          }
        __builtin_amdgcn_s_setprio(1);
#pragma unroll
        for (int kc = 0; kc < 2; ++kc) {
          const int eoff = lr * 72 + kc * 32 + lg * 8;
          const s16x8 pa = *(const s16x8*)(PH + eoff);
          const s16x8 pb = *(const s16x8*)(PL + eoff);
#pragma unroll
          for (int nf = 0; nf < 4; ++nf) {
            const int d = nf * 16 + lr;
            const int pcx = (kc * 4 + lg) ^ (d & 7);
            const char* vb = lds + 16384 + d * 128 + pcx * 16;
            const s16x8 vh = *(const s16x8*)(vb);
            const s16x8 vl = *(const s16x8*)(vb + 8192);
            acc[nf] = __builtin_amdgcn_mfma_f32_16x16x32_bf16(pa, vh, acc[nf], 0, 0, 0);
            acc[nf] = __builtin_amdgcn_mfma_f32_16x16x32_bf16(pa, vl, acc[nf], 0, 0, 0);
            acc[nf] = __builtin_amdgcn_mfma_f32_16x16x32_bf16(pb, vh, acc[nf], 0, 0, 0);
          }
        }
        __builtin_amdgcn_s_setprio(0);
      }
      __syncthreads();
    }
#pragma unroll
    for (int r = 0; r < 4; ++r) {
      const float inv = 1.0f / lsum[r];
      const size_t tok = (size_t)(b * S_SEQ + q0 + w * 16 + 4 * lg + r);
#pragma unroll
      for (int nf = 0; nf < 4; ++nf) {
        const float v = acc[nf][r] * inv;
        const unsigned short hb = f32_to_bf16_rn(v);
        const size_t o = tok * DM + h * 64 + nf * 16 + lr;
        ctxH[o] = hb;
        ctxL[o] = f32_to_bf16_rn(v - bf16_to_f32(hb));
      }
    }
  }
}

// ------------------------------------------------------------- launch
extern "C" void kernel_launch(void* const* d_in, const int* in_sizes, int n_in,
                              void* d_out, int out_size, void* d_ws, size_t ws_size,
                              hipStream_t stream)
{
  const float* x   = (const float*)d_in[0];
  const float* Wq  = (const float*)d_in[1];
  const float* Wk  = (const float*)d_in[2];
  const float* Wv  = (const float*)d_in[3];
  const float* Wo  = (const float*)d_in[4];
  const float* ln1 = (const float*)d_in[5];
  const float* ln2 = (const float*)d_in[6];
  const float* w1  = (const float*)d_in[7];
  const float* w2  = (const float*)d_in[8];
  const float* w3  = (const float*)d_in[9];
  float* out = (float*)d_out;
  char* ws = (char*)d_ws;
  const size_t MB = 1024 * 1024;

  // ws layout, peak exactly 160 MB (phase-overlaid; liveness audited r6)
  unsigned short* WqkvH = (unsigned short*)(ws + 0 * MB);   // [3072][1024]
  unsigned short* WqkvL = (unsigned short*)(ws + 6 * MB);
  unsigned short* WoH = (unsigned short*)(ws + 12 * MB);
  unsigned short* WoL = (unsigned short*)(ws + 14 * MB);
  unsigned short* w1H = (unsigned short*)(ws + 16 * MB);
  unsigned short* w1L = (unsigned short*)(ws + 24 * MB);
  unsigned short* w2H = (unsigned short*)(ws + 32 * MB);
  unsigned short* w2L = (unsigned short*)(ws + 40 * MB);
  unsigned short* w3H = (unsigned short*)(ws + 48 * MB);
  unsigned short* w3L = (unsigned short*)(ws + 56 * MB);
  unsigned short* hH  = (unsigned short*)(ws + 64 * MB);
  unsigned short* hL  = (unsigned short*)(ws + 72 * MB);
  unsigned short* QHp = (unsigned short*)(ws + 80 * MB);   // gemm -> attn
  unsigned short* QLp = (unsigned short*)(ws + 88 * MB);
  unsigned short* KHp = (unsigned short*)(ws + 96 * MB);
  unsigned short* KLp = (unsigned short*)(ws + 104 * MB);
  unsigned short* VHp = (unsigned short*)(ws + 112 * MB);  // gemm -> vt_split
  unsigned short* VLp = (unsigned short*)(ws + 120 * MB);
  unsigned short* VtH = (unsigned short*)(ws + 128 * MB);  // vt_split -> attn
  unsigned short* VtL = (unsigned short*)(ws + 136 * MB);
  unsigned short* ctxH = (unsigned short*)(ws + 144 * MB); // attn -> Wo gemm
  unsigned short* ctxL = (unsigned short*)(ws + 152 * MB);
  float* tab = (float*)(ws + 159 * MB + 512 * 1024);       // start -> rope (ctxL tail)
  float* x2  = (float*)(ws + 112 * MB);                    // Wo gemm -> end (V planes dead)
  unsigned short* t1H = (unsigned short*)(ws + 80 * MB);   // FFN overlays (Q/K dead)
  unsigned short* t1L = (unsigned short*)(ws + 128 * MB);  // (Vt/ctx dead)

  rope_table<<<256, 256, 0, stream>>>(tab);
  split_planes<<<1024, 256, 0, stream>>>(Wq, WqkvH, WqkvL, 1024 * 1024 / 4);
  split_planes<<<1024, 256, 0, stream>>>(Wk, WqkvH + 1024 * 1024, WqkvL + 1024 * 1024, 1024 * 1024 / 4);
  split_planes<<<1024, 256, 0, stream>>>(Wv, WqkvH + 2048 * 1024, WqkvL + 2048 * 1024, 1024 * 1024 / 4);
  split_planes<<<1024, 256, 0, stream>>>(Wo, WoH, WoL, 1024 * 1024 / 4);
  split_planes<<<4096, 256, 0, stream>>>(w1, w1H, w1L, 4096 * 1024 / 4);
  split_planes<<<4096, 256, 0, stream>>>(w2, w2H, w2L, 4096 * 1024 / 4);
  split_planes<<<4096, 256, 0, stream>>>(w3, w3H, w3L, 4096 * 1024 / 4);

  // 1) h = rmsnorm(x, ln1) -> planes
  rmsnorm_planes<<<T_TOK, 256, 0, stream>>>(x, ln1, hH, hL);
  // 2) fused QKV: [Q|K|V] planes, N=3072
  gemm8<256, 5><<<192, 512, 0, stream>>>(hH, hL, WqkvH, WqkvL, nullptr, nullptr,
                                         QHp, QLp, KHp, KLp, VHp, VLp,
                                         3072, DM, DM, DM, 12);
  // 3) RoPE on Q,K planes; V^T planes
  rope_apply_planes<<<T_TOK, 256, 0, stream>>>(QHp, QLp, KHp, KLp, tab);
  vt_split<<<dim3(32, NH, 2), 256, 0, stream>>>(VHp, VLp, VtH, VtL);
  // 4) ctx planes = causal attention (paired q-tiles)
  attn_mfma<<<dim3(16, NH, 2), 256, 0, stream>>>(QHp, QLp, KHp, KLp, VtH, VtL, ctxH, ctxL);
  // 5) x2 = x + ctx @ Wo^T
  gemm8<128, 1><<<128, 512, 0, stream>>>(ctxH, ctxL, WoH, WoL, x, x2,
                                         nullptr, nullptr, nullptr, nullptr, nullptr, nullptr,
                                         DM, DM, DM, DM, 8);
  // 6) h2 = rmsnorm(x2, ln2) -> planes
  rmsnorm_planes<<<T_TOK, 256, 0, stream>>>(x2, ln2, hH, hL);
  // 7) t1 = silu(h2 @ w1^T) planes, N=4096
  gemm8<256, 2><<<256, 512, 0, stream>>>(hH, hL, w1H, w1L, nullptr, nullptr,
                                         t1H, t1L, nullptr, nullptr, nullptr, nullptr,
                                         DFF, DM, DM, DM, 16);
  // 8) u = t1 .* (h2 @ w3^T) planes, in-place over t1
  gemm8<256, 3><<<256, 512, 0, stream>>>(hH, hL, w3H, w3L, nullptr, nullptr,
                                         t1H, t1L, nullptr, nullptr, nullptr, nullptr,
                                         DFF, DM, DM, DM, 16);
  // 9) out = x2 + u @ w2^T, K=4096
  gemm8<128, 1><<<128, 512, 0, stream>>>(t1H, t1L, w2H, w2L, x2, out,
                                         nullptr, nullptr, nullptr, nullptr, nullptr, nullptr,
                                         DM, DFF, DFF, DFF, 8);
}